// Round 4
// baseline (3359.174 us; speedup 1.0000x reference)
//
#include <hip/hip_runtime.h>

#define TT  464
#define HH  256
#define BB  64
#define NWG 64   // persistent LSTM workgroups: 2 batch-groups x 32 feature-groups

using bf16x8 = __attribute__((ext_vector_type(8))) short;   // 8 bf16 (4 VGPRs)
using f32x4  = __attribute__((ext_vector_type(4))) float;   // MFMA accumulator
typedef unsigned long long u64;
typedef unsigned int u32;

__device__ __forceinline__ unsigned short f2bf(float x) {
  union { float f; unsigned u; } v; v.f = x;
  unsigned r = v.u + 0x7fffu + ((v.u >> 16) & 1u);   // RNE
  return (unsigned short)(r >> 16);
}

// Persistent LSTM, latency-optimized:
//  - h exchange is POLL-THE-DATA: each element published as u32 (tag<<16|bf16)
//    via relaxed agent atomic store; consumers poll tagged u64 pairs until all
//    tags match the step. No flags, no producer vmcnt drain, no fences:
//    one fabric trip per step instead of three.
//  - Weights live in VGPRs (16 bf16x8/lane), x A-fragments register-direct
//    (prefetched floats), z exchange via double-buffered LDS + ONE barrier/step.
//  - 64 wgs on 256 CUs -> 1 wave/SIMD: ~290 VGPR/lane is free.
__global__ __launch_bounds__(256, 1) void lstm_kernel(
    const float* __restrict__ x,      // [64][464][256]
    const float* __restrict__ h0,     // [64][256]
    const float* __restrict__ c0,     // [64][256]
    const float* __restrict__ W,      // [256][1024]
    const float* __restrict__ U,      // [256][1024]
    const float* __restrict__ bias,   // [1024]
    u32* __restrict__ h_bufs,         // [2][64][256] tagged u32 (memset 0 at launch)
    unsigned short* __restrict__ seq, // [64][464][256] bf16
    float* __restrict__ out)          // d_out: [0:16384) core, [16384) hT, [32768) cT
{
  const int tid = threadIdx.x;
  const int wg  = blockIdx.x;
  const int bgi = wg >> 5;          // 0..1 batch group
  const int fgi = wg & 31;          // 0..31 feature group (8 hidden units)
  const int wv  = tid >> 6;         // wave 0..3
  const int ln  = tid & 63;
  const int mt  = wv >> 1;          // M-tile (16 rows)
  const int nt  = wv & 1;           // N-tile (16 gate cols)
  const int l15 = ln & 15;
  const int q   = ln >> 4;

  __shared__ float z_lds[2][32][36];   // double-buffered MFMA result exchange

  // ---- weights into registers: B[n = nt*16+l15][k = kk*32+q*8+j] ----
  // z col n -> gate g=n>>3, unit j=n&7 -> global col g*256 + fgi*8 + j
  const int n  = nt * 16 + l15;
  const int gc = (n >> 3) * 256 + fgi * 8 + (n & 7);
  bf16x8 Bw[8], Bu[8];
#pragma unroll
  for (int kk = 0; kk < 8; ++kk) {
#pragma unroll
    for (int j = 0; j < 8; ++j) {
      const int k = kk * 32 + q * 8 + j;
      Bw[kk][j] = (short)f2bf(W[(size_t)k * 1024 + gc]);
      Bu[kk][j] = (short)f2bf(U[(size_t)k * 1024 + gc]);
    }
  }

  // ---- per-thread owned state: one (batch-row, hidden-unit) pair ----
  const int r_own = tid >> 3;        // 0..31
  const int j_own = tid & 7;         // 0..7
  const int brow  = bgi * 32 + r_own;
  const int col   = fgi * 8 + j_own;
  float c = c0[brow * HH + col];
  float h = h0[brow * HH + col];
  const float b_i = bias[        col];
  const float b_f = bias[  HH  + col];
  const float b_g = bias[2*HH  + col];
  const float b_o = bias[3*HH  + col];

  // publish h0: tag 1, buffer 0
  __hip_atomic_store(&h_bufs[brow * HH + col],
                     (1u << 16) | (u32)f2bf(h),
                     __ATOMIC_RELAXED, __HIP_MEMORY_SCOPE_AGENT);

  // ---- x register prefetch: lane's A row = bgi*32 + mt*16 + l15 ----
  const int arow = bgi * 32 + mt * 16 + l15;
  const float* xbase = x + (size_t)arow * TT * HH + q * 8;
  float4 xf[16];
#pragma unroll
  for (int kk = 0; kk < 8; ++kk) {
    xf[2*kk]   = *(const float4*)(xbase + kk * 32);
    xf[2*kk+1] = *(const float4*)(xbase + kk * 32 + 4);
  }

  // tagged-u64 poll base for this lane's h fragment rows
  const u64* hrow0 = (const u64*)(h_bufs + arow * HH + q * 8);
  const u64* hrow1 = (const u64*)(h_bufs + BB * HH + arow * HH + q * 8);

  for (int t = 0; t < TT; ++t) {
    const int pr = t & 1;

    // convert prefetched x[t] -> A fragments
    bf16x8 xa[8];
#pragma unroll
    for (int kk = 0; kk < 8; ++kk) {
      union { u32 u[4]; bf16x8 v; } tmp;
      tmp.u[0] = (u32)f2bf(xf[2*kk].x)   | ((u32)f2bf(xf[2*kk].y)   << 16);
      tmp.u[1] = (u32)f2bf(xf[2*kk].z)   | ((u32)f2bf(xf[2*kk].w)   << 16);
      tmp.u[2] = (u32)f2bf(xf[2*kk+1].x) | ((u32)f2bf(xf[2*kk+1].y) << 16);
      tmp.u[3] = (u32)f2bf(xf[2*kk+1].z) | ((u32)f2bf(xf[2*kk+1].w) << 16);
      xa[kk] = tmp.v;
    }

    // x @ W half (register A and B, no LDS, no h dependency)
    f32x4 acc = {0.f, 0.f, 0.f, 0.f};
#pragma unroll
    for (int kk = 0; kk < 8; ++kk)
      acc = __builtin_amdgcn_mfma_f32_16x16x32_bf16(xa[kk], Bw[kk], acc, 0, 0, 0);

    // ---- poll tagged h: 32 u64 loads, all tags must equal t+1 ----
    const u64* hp = pr ? hrow1 : hrow0;
    const u64 expd = ((u64)(u32)(t + 1) << 48) | ((u64)(u32)(t + 1) << 16);
    u64 hv[32];
    for (;;) {
      u64 orv = 0;
#pragma unroll
      for (int kk = 0; kk < 8; ++kk)
#pragma unroll
        for (int pair = 0; pair < 4; ++pair) {
          u64 v = __hip_atomic_load(hp + kk * 16 + pair,
                                    __ATOMIC_RELAXED, __HIP_MEMORY_SCOPE_AGENT);
          hv[kk * 4 + pair] = v;
          orv |= v ^ expd;
        }
      if (__all((orv & 0xFFFF0000FFFF0000ull) == 0)) break;
    }

    // extract bf16 pairs -> h fragments, h @ U half
#pragma unroll
    for (int kk = 0; kk < 8; ++kk) {
      union { u32 u[4]; bf16x8 v; } tmp;
#pragma unroll
      for (int pair = 0; pair < 4; ++pair) {
        u64 v = hv[kk * 4 + pair];
        tmp.u[pair] = ((u32)v & 0xFFFFu) | ((u32)(v >> 32) << 16);
      }
      acc = __builtin_amdgcn_mfma_f32_16x16x32_bf16(tmp.v, Bu[kk], acc, 0, 0, 0);
    }

    // z exchange (C/D layout: col=lane&15, row=(lane>>4)*4+reg)
#pragma unroll
    for (int reg = 0; reg < 4; ++reg)
      z_lds[pr][mt * 16 + q * 4 + reg][nt * 16 + l15] = acc[reg];

    __syncthreads();                 // the ONLY barrier per step

    // gates: z col g*8 + j
    float zi = z_lds[pr][r_own][      j_own] + b_i;
    float zf = z_lds[pr][r_own][ 8 + j_own] + b_f;
    float zg = z_lds[pr][r_own][16 + j_own] + b_g;
    float zo = z_lds[pr][r_own][24 + j_own] + b_o;
    float gi = 1.f / (1.f + __expf(-zi));
    float gf = 1.f / (1.f + __expf(-zf));
    float go = 1.f / (1.f + __expf(-zo));
    float gg = fmaxf(zg, 0.f);
    c = gf * c + gi * gg;
    h = go * fmaxf(c, 0.f);
    const unsigned short hb16 = f2bf(h);
    seq[((size_t)brow * TT + t) * HH + col] = hb16;

    // publish h_{t+1}: tag t+2, buffer (t+1)&1 — no drain, consumers poll tags
    __hip_atomic_store(&h_bufs[((t + 1) & 1) * (BB * HH) + brow * HH + col],
                       ((u32)(t + 2) << 16) | (u32)hb16,
                       __ATOMIC_RELAXED, __HIP_MEMORY_SCOPE_AGENT);

    // prefetch x[t+1]
    const int tn = (t + 1 < TT) ? (t + 1) : (TT - 1);
#pragma unroll
    for (int kk = 0; kk < 8; ++kk) {
      xf[2*kk]   = *(const float4*)(xbase + (size_t)tn * HH + kk * 32);
      xf[2*kk+1] = *(const float4*)(xbase + (size_t)tn * HH + kk * 32 + 4);
    }
  }

  out[16384 + brow * HH + col] = h;   // hT fp32 (un-rounded state)
  out[32768 + brow * HH + col] = c;   // cT
}

// Dense partials: wg kb handles t = kb and kb+232; K=512 per wg.
// Wd staged via coalesced float4 loads into LDS (aliased with A-tile), read-time bf16.
#define DP_PA 264   // a_lds pitch (shorts)
#define DP_PW 258   // Wf pitch (floats): 258%32=2 -> 2-way on frag reads (free)
__global__ __launch_bounds__(256) void dense_partial(
    const unsigned short* __restrict__ seq,  // [64][464][256] bf16
    const float* __restrict__ Wd,            // [118784][256]
    float* __restrict__ part)                // [232][64][256]
{
  __shared__ __align__(16) char smem[64 * DP_PA * 2];   // 33792 B >= 32*DP_PW*4
  unsigned short* a_lds = (unsigned short*)smem;
  float*          Wf    = (float*)smem;

  const int kb  = blockIdx.x;     // 0..231
  const int tid = threadIdx.x;
  const int wv  = tid >> 6;       // M-tile
  const int ln  = tid & 63;
  const int l15 = ln & 15;
  const int q   = ln >> 4;

  f32x4 acc[16];
#pragma unroll
  for (int i = 0; i < 16; ++i) acc[i] = (f32x4){0.f, 0.f, 0.f, 0.f};

  for (int half = 0; half < 2; ++half) {
    const int t = kb + half * 232;
    __syncthreads();                       // prev chunk's Wf reads done (smem reuse)
#pragma unroll
    for (int it = 0; it < 8; ++it) {       // stage A: seq[0..63][t][:]
      int cidx = it * 256 + tid;
      int row  = cidx >> 5;
      int off  = (cidx & 31) * 8;
      *(bf16x8*)&a_lds[row * DP_PA + off] =
          *(const bf16x8*)(seq + ((size_t)row * TT + t) * HH + off);
    }
    __syncthreads();
    bf16x8 af[8];
#pragma unroll
    for (int kk = 0; kk < 8; ++kk)
      af[kk] = *(const bf16x8*)&a_lds[(wv * 16 + l15) * DP_PA + kk * 32 + q * 8];

    for (int ck = 0; ck < 8; ++ck) {       // K chunks of 32
      __syncthreads();                     // af in regs / prev Wf reads done
#pragma unroll
      for (int it = 0; it < 8; ++it) {     // stage Wf[32][256] fp32, coalesced
        int idx = it * 256 + tid;
        int r   = idx >> 6;
        int c4  = (idx & 63) * 4;
        float4 v = *(const float4*)(Wd + ((size_t)(t * 256 + ck * 32 + r)) * HH + c4);
        *(float2*)&Wf[r * DP_PW + c4]     = make_float2(v.x, v.y);
        *(float2*)&Wf[r * DP_PW + c4 + 2] = make_float2(v.z, v.w);
      }
      __syncthreads();
#pragma unroll
      for (int nt2 = 0; nt2 < 16; ++nt2) {
        const int nn = nt2 * 16 + l15;
        bf16x8 bfr;
#pragma unroll
        for (int j = 0; j < 8; ++j)
          bfr[j] = (short)f2bf(Wf[(q * 8 + j) * DP_PW + nn]);
        acc[nt2] = __builtin_amdgcn_mfma_f32_16x16x32_bf16(af[ck], bfr, acc[nt2], 0, 0, 0);
      }
    }
  }

  float* pb = part + (size_t)kb * (BB * HH);
#pragma unroll
  for (int nt2 = 0; nt2 < 16; ++nt2)
#pragma unroll
    for (int reg = 0; reg < 4; ++reg)
      pb[(wv * 16 + q * 4 + reg) * HH + nt2 * 16 + l15] = acc[nt2][reg];
}

__global__ __launch_bounds__(256) void dense_reduce(
    const float* __restrict__ part,   // [232][16384]
    const float* __restrict__ bd,     // [256]
    float* __restrict__ out)          // d_out[0:16384)
{
  const int o = blockIdx.x * 256 + threadIdx.x;
  float s0 = 0.f, s1 = 0.f, s2 = 0.f, s3 = 0.f;
  for (int kb = 0; kb < 232; kb += 4) {
    s0 += part[(size_t)(kb    ) * 16384 + o];
    s1 += part[(size_t)(kb + 1) * 16384 + o];
    s2 += part[(size_t)(kb + 2) * 16384 + o];
    s3 += part[(size_t)(kb + 3) * 16384 + o];
  }
  float s = (s0 + s1) + (s2 + s3) + bd[o & 255];
  out[o] = fmaxf(s, 0.f);
}

extern "C" void kernel_launch(void* const* d_in, const int* in_sizes, int n_in,
                              void* d_out, int out_size, void* d_ws, size_t ws_size,
                              hipStream_t stream) {
  const float* x  = (const float*)d_in[0];
  const float* h0 = (const float*)d_in[1];
  const float* c0 = (const float*)d_in[2];
  const float* W  = (const float*)d_in[3];
  const float* U  = (const float*)d_in[4];
  const float* bv = (const float*)d_in[5];
  const float* Wd = (const float*)d_in[6];
  const float* bd = (const float*)d_in[7];
  float* out = (float*)d_out;

  // d_ws layout:
  //   [0, 128K)      h_bufs  [2][64][256] tagged u32  (memset 0: tag-clean)
  //   next 15.2 MB   seq     [64][464][256] bf16
  //   next 15.2 MB   part    [232][64][256] fp32      (total ~30.5 MB)
  char* w = (char*)d_ws;
  u32*            h_bufs = (u32*)w;
  unsigned short* seq    = (unsigned short*)(w + 2 * BB * HH * 4);
  float*          part   = (float*)(w + 2 * BB * HH * 4 + (size_t)BB * TT * HH * 2);

  hipMemsetAsync(h_bufs, 0, 2 * BB * HH * 4, stream);   // clean tags every launch
  lstm_kernel<<<NWG, 256, 0, stream>>>(x, h0, c0, W, U, bv, h_bufs, seq, out);
  dense_partial<<<232, 256, 0, stream>>>(seq, Wd, part);
  dense_reduce<<<64, 256, 0, stream>>>(part, bd, out);
}